// Round 6
// baseline (174.560 us; speedup 1.0000x reference)
//
#include <hip/hip_runtime.h>

// L1 attention: out[b,i,j,h] = -0.125 * sum_d |q[b,i,h,d] - k[b,j,h,d]|
// B=2, T=512, H=8, D=64.  out (B,T,T,H), h innermost.
//
// v6: d-split wave layout for occupancy + register-only output.
//  - lane = (half, jrow): lanes 0-31 handle j-rows d[0:32), lanes 32-63 the
//    SAME j-rows d[32:64).  k per lane = 8 float4 per h (32 VGPR).
//  - wave w owns i = i0 + 4w + r (r=0..3); acc[4][8] (i x h) in 32 VGPRs.
//  - q tile (16 i x 8 h x 64 d = 32 KB) staged in LDS once; inner reads are
//    2-address-broadcast ds_read_b128 (same banks, 2-way = free).
//  - cross-half d-reduction via __shfl_xor(.,32); writeout is one fully
//    contiguous 1 KB wave-store per i (lane<32 stores h0-3, lane>=32 h4-7).
//  - 1024 blocks x 4 waves = 4096 waves = 4/SIMD; LDS 32 KB -> 4 blocks/CU.

#define TDIM 512
#define HDIM 8
#define DDIM 64
#define HD   (HDIM * DDIM)      // 512
#define JT   32
#define IT   16

__global__ __launch_bounds__(256, 4) void l1attn_kernel(
    const float* __restrict__ q, const float* __restrict__ k,
    float* __restrict__ out)
{
    __shared__ float qs[IT * HD];            // 32768 B

    const int t    = threadIdx.x;
    const int lane = t & 63;
    const int w    = t >> 6;                 // wave id 0..3
    const int j0   = blockIdx.x * JT;
    const int i0   = blockIdx.y * IT;
    const int b    = blockIdx.z;

    // ---- stage q tile once: 16 rows x 512 floats = 2048 float4, 8/thread ----
    #pragma unroll
    for (int v = 0; v < 8; ++v) {
        int chunk = v * 256 + t;
        int row   = chunk >> 7;              // 0..15
        int col4  = chunk & 127;             // 0..127
        *(float4*)&qs[row * HD + col4 * 4] =
            *(const float4*)(q + ((size_t)(b * TDIM + i0 + row)) * HD + col4 * 4);
    }
    __syncthreads();

    const int jrow = lane & 31;              // j within tile
    const int half = lane >> 5;              // d-half: 0 -> d[0:32), 1 -> d[32:64)
    const float* kbase = k + ((size_t)(b * TDIM + j0 + jrow)) * HD + half * 32;
    const float* qw    = &qs[(4 * w) * HD + half * 32];

    float acc[4][8];
    #pragma unroll
    for (int r = 0; r < 4; ++r)
        #pragma unroll
        for (int h = 0; h < 8; ++h) acc[r][h] = 0.f;

    #pragma unroll
    for (int h = 0; h < 8; ++h) {
        // lane's 128B k-slice for this h (contiguous -> L1-friendly)
        float4 kc[8];
        #pragma unroll
        for (int c = 0; c < 8; ++c)
            kc[c] = *(const float4*)(kbase + h * DDIM + c * 4);

        #pragma unroll
        for (int c = 0; c < 8; ++c) {
            #pragma unroll
            for (int r = 0; r < 4; ++r) {
                float4 qv = *(const float4*)&qw[r * HD + h * DDIM + c * 4];
                float d0 = qv.x - kc[c].x, d1 = qv.y - kc[c].y;
                float d2 = qv.z - kc[c].z, d3 = qv.w - kc[c].w;
                acc[r][h] += (fabsf(d0) + fabsf(d1)) + (fabsf(d2) + fabsf(d3));
            }
        }
    }

    // ---- cross-half reduction: lane l and l^32 hold the two d-halves ----
    #pragma unroll
    for (int r = 0; r < 4; ++r)
        #pragma unroll
        for (int h = 0; h < 8; ++h)
            acc[r][h] += __shfl_xor(acc[r][h], 32);

    // ---- writeout: per i, one contiguous 1 KB wave-store (32 j x 8 h) ----
    #pragma unroll
    for (int r = 0; r < 4; ++r) {
        float4 lo = make_float4(acc[r][0], acc[r][1], acc[r][2], acc[r][3]);
        float4 hi = make_float4(acc[r][4], acc[r][5], acc[r][6], acc[r][7]);
        float4 sel;
        sel.x = (half ? hi.x : lo.x) * -0.125f;
        sel.y = (half ? hi.y : lo.y) * -0.125f;
        sel.z = (half ? hi.z : lo.z) * -0.125f;
        sel.w = (half ? hi.w : lo.w) * -0.125f;
        size_t base = (((size_t)(b * TDIM + i0 + 4 * w + r)) * TDIM + j0) * HDIM;
        *(float4*)(out + base + jrow * HDIM + half * 4) = sel;
    }
}

extern "C" void kernel_launch(void* const* d_in, const int* in_sizes, int n_in,
                              void* d_out, int out_size, void* d_ws, size_t ws_size,
                              hipStream_t stream) {
    const float* q = (const float*)d_in[0];
    const float* k = (const float*)d_in[1];
    float* out = (float*)d_out;
    const int B = in_sizes[0] / (TDIM * HD);   // = 2
    dim3 grid(TDIM / JT, TDIM / IT, B);         // (16, 32, 2)
    l1attn_kernel<<<grid, 256, 0, stream>>>(q, k, out);
}

// Round 7
// 93.751 us; speedup vs baseline: 1.8620x; 1.8620x over previous
//
#include <hip/hip_runtime.h>

// L1 attention: out[b,i,j,h] = -0.125 * sum_d |q[b,i,h,d] - k[b,j,h,d]|
// B=2, T=512, H=8, D=64.  out (B,T,T,H), h innermost.
//
// v7 = v6 structure with the spill fixed.
// R6 failure: __launch_bounds__(256,4) made the compiler cap at the 64-VGPR
// occupancy step; kc[8]+acc[4][8] (~80-100 live) spilled to scratch ->
// 268 MB of spill R/W traffic (the measured FETCH/WRITE blowup).
// Fix: (256,2) bound (R5 got 104 VGPR under it) + kc[4] two-chunk h-body
// so peak demand ~60-70 regs.  VGPR in 65..128 -> 16 waves/CU (4/SIMD),
// LDS 32 KB -> 4 blocks/CU.  Layout unchanged:
//  - lane = (half,jrow): lanes 0-31 j-rows d[0:32), lanes 32-63 d[32:64).
//  - q tile in LDS once; inner q reads are 2-address wave-broadcast
//    ds_read_b128 (conflict-free).
//  - cross-half reduce via __shfl_xor(.,32); writeout 1 KB contiguous per
//    (wave,i) directly from registers (R5/R6 proved WRITE=output exactly).

#define TDIM 512
#define HDIM 8
#define DDIM 64
#define HD   (HDIM * DDIM)      // 512
#define JT   32
#define IT   16

__global__ __launch_bounds__(256, 2) void l1attn_kernel(
    const float* __restrict__ q, const float* __restrict__ k,
    float* __restrict__ out)
{
    __shared__ float qs[IT * HD];            // 32768 B

    const int t    = threadIdx.x;
    const int lane = t & 63;
    const int w    = t >> 6;                 // wave id 0..3
    const int j0   = blockIdx.x * JT;
    const int i0   = blockIdx.y * IT;
    const int b    = blockIdx.z;

    // ---- stage q tile once: 16 rows x 512 floats = 2048 float4, 8/thread ----
    #pragma unroll
    for (int v = 0; v < 8; ++v) {
        int chunk = v * 256 + t;
        int row   = chunk >> 7;              // 0..15
        int col4  = chunk & 127;             // 0..127
        *(float4*)&qs[row * HD + col4 * 4] =
            *(const float4*)(q + ((size_t)(b * TDIM + i0 + row)) * HD + col4 * 4);
    }
    __syncthreads();

    const int jrow = lane & 31;              // j within tile
    const int half = lane >> 5;              // d-half: 0 -> d[0:32), 1 -> d[32:64)
    const float* kbase = k + ((size_t)(b * TDIM + j0 + jrow)) * HD + half * 32;
    const float* qw    = &qs[(4 * w) * HD + half * 32];

    float acc[4][8];
    #pragma unroll
    for (int r = 0; r < 4; ++r)
        #pragma unroll
        for (int h = 0; h < 8; ++h) acc[r][h] = 0.f;

    #pragma unroll
    for (int h = 0; h < 8; ++h) {
        #pragma unroll
        for (int cc = 0; cc < 2; ++cc) {
            // lane's 64B k-chunk for this (h, cc)
            float4 kc[4];
            #pragma unroll
            for (int c = 0; c < 4; ++c)
                kc[c] = *(const float4*)(kbase + h * DDIM + cc * 16 + c * 4);

            #pragma unroll
            for (int c = 0; c < 4; ++c) {
                #pragma unroll
                for (int r = 0; r < 4; ++r) {
                    float4 qv = *(const float4*)&qw[r * HD + h * DDIM + cc * 16 + c * 4];
                    float d0 = qv.x - kc[c].x, d1 = qv.y - kc[c].y;
                    float d2 = qv.z - kc[c].z, d3 = qv.w - kc[c].w;
                    acc[r][h] += (fabsf(d0) + fabsf(d1)) + (fabsf(d2) + fabsf(d3));
                }
            }
        }
    }

    // ---- cross-half reduction: lane l and l^32 hold the two d-halves ----
    #pragma unroll
    for (int r = 0; r < 4; ++r)
        #pragma unroll
        for (int h = 0; h < 8; ++h)
            acc[r][h] += __shfl_xor(acc[r][h], 32);

    // ---- writeout: per i, one contiguous 1 KB wave-store (32 j x 8 h) ----
    #pragma unroll
    for (int r = 0; r < 4; ++r) {
        float4 lo = make_float4(acc[r][0], acc[r][1], acc[r][2], acc[r][3]);
        float4 hi = make_float4(acc[r][4], acc[r][5], acc[r][6], acc[r][7]);
        float4 sel;
        sel.x = (half ? hi.x : lo.x) * -0.125f;
        sel.y = (half ? hi.y : lo.y) * -0.125f;
        sel.z = (half ? hi.z : lo.z) * -0.125f;
        sel.w = (half ? hi.w : lo.w) * -0.125f;
        size_t base = (((size_t)(b * TDIM + i0 + 4 * w + r)) * TDIM + j0) * HDIM;
        *(float4*)(out + base + jrow * HDIM + half * 4) = sel;
    }
}

extern "C" void kernel_launch(void* const* d_in, const int* in_sizes, int n_in,
                              void* d_out, int out_size, void* d_ws, size_t ws_size,
                              hipStream_t stream) {
    const float* q = (const float*)d_in[0];
    const float* k = (const float*)d_in[1];
    float* out = (float*)d_out;
    const int B = in_sizes[0] / (TDIM * HD);   // = 2
    dim3 grid(TDIM / JT, TDIM / IT, B);         // (16, 32, 2)
    l1attn_kernel<<<grid, 256, 0, stream>>>(q, k, out);
}